// Round 6
// baseline (913.368 us; speedup 1.0000x reference)
//
#include <hip/hip_runtime.h>
#include <stdint.h>

// VectorQuantizer — z:(16,256,64,64) f32 -> 65536 rows of 256; emb:(1024,256) f32.
// d_out: q[16777216] | vq_loss[1] | idx_as_float[65536]
//
// R6: R5 + software-pipelined e-loads (named-register double buffer, depth 1,
// pipelined across dc and across kc). R5 showed VALUBusy=46% with zero
// conflicts and zero spill: per-iteration L2 latency was exposed because
// e-loads were consumed in the issuing iteration. FMA order per accumulator
// is IDENTICAL to R5 -> bit-identical results.

#define WAITVM(N) asm volatile("s_waitcnt vmcnt(" #N ")" ::: "memory")

__device__ __forceinline__ void gload16(const float* gp, float* lp) {
    __builtin_amdgcn_global_load_lds(
        (const __attribute__((address_space(1))) void*)gp,
        (__attribute__((address_space(3))) void*)lp, 16, 0, 0);
}

// ---------------- kernel 0: embedding row norms ----------------
__global__ __launch_bounds__(256)
void enorm_kernel(const float* __restrict__ emb, float* __restrict__ enorm) {
    const int wv = threadIdx.x >> 6, ln = threadIdx.x & 63;
    const int k = blockIdx.x * 4 + wv;
    const float4 v = *reinterpret_cast<const float4*>(emb + (size_t)k * 256 + ln * 4);
    float s = v.x * v.x + v.y * v.y + v.z * v.z + v.w * v.w;
#pragma unroll
    for (int off = 32; off > 0; off >>= 1) s += __shfl_xor(s, off);
    if (ln == 0) enorm[k] = s;
}

// ---------------- kernel 1: argmin (dq-specialized, e-pipelined) ----------------
// 256 thr = 4 waves. Wave wv owns rows wv*16+m (m=0..15).
// Lane: dq = tid&3 (d-quarter), tx = (tid>>2)&15 (code lane).
// Chunk kc (64 codes): thread's codes = kc*64 + c*16 + tx, c=0..3.

#define LOADE(E0, E1, E2, E3, KC, DC) { \
    const float* eb_ = emb + (size_t)((KC) * 64 + tx) * 256 + (DC) * 16 + dq * 4; \
    E0 = *reinterpret_cast<const float4*>(eb_); \
    E1 = *reinterpret_cast<const float4*>(eb_ + 16 * 256); \
    E2 = *reinterpret_cast<const float4*>(eb_ + 32 * 256); \
    E3 = *reinterpret_cast<const float4*>(eb_ + 48 * 256); }

#define COMP(E0, E1, E2, E3, DC) { \
    _Pragma("unroll") \
    for (int m = 0; m < 16; ++m) { \
        const float4 a = *reinterpret_cast<const float4*>( \
            &z_lds[zbase + m * 256 + (DC) * 16]);   /* 16-lane broadcast */ \
        acc[m][0] = fmaf(a.x, E0.x, acc[m][0]); acc[m][0] = fmaf(a.y, E0.y, acc[m][0]); \
        acc[m][0] = fmaf(a.z, E0.z, acc[m][0]); acc[m][0] = fmaf(a.w, E0.w, acc[m][0]); \
        acc[m][1] = fmaf(a.x, E1.x, acc[m][1]); acc[m][1] = fmaf(a.y, E1.y, acc[m][1]); \
        acc[m][1] = fmaf(a.z, E1.z, acc[m][1]); acc[m][1] = fmaf(a.w, E1.w, acc[m][1]); \
        acc[m][2] = fmaf(a.x, E2.x, acc[m][2]); acc[m][2] = fmaf(a.y, E2.y, acc[m][2]); \
        acc[m][2] = fmaf(a.z, E2.z, acc[m][2]); acc[m][2] = fmaf(a.w, E2.w, acc[m][2]); \
        acc[m][3] = fmaf(a.x, E3.x, acc[m][3]); acc[m][3] = fmaf(a.y, E3.y, acc[m][3]); \
        acc[m][3] = fmaf(a.z, E3.z, acc[m][3]); acc[m][3] = fmaf(a.w, E3.w, acc[m][3]); } }

__global__ __launch_bounds__(256, 1)
void argmin_kernel(const float* __restrict__ z, const float* __restrict__ emb,
                   const float* __restrict__ enorm_g, float* __restrict__ idx_out) {
    __shared__ float z_lds[16384];   // [row][d] linear, 64 KB
    __shared__ float znbuf[64];

    const int tid = threadIdx.x;
    const int dq = tid & 3;
    const int tx = (tid >> 2) & 15;
    const int wv = tid >> 6;
    const int ln = tid & 63;

    const float* zblk = z + (size_t)blockIdx.x * 16384;

    // ---- DMA z tile to LDS (linear dest = linear source) ----
#pragma unroll
    for (int c = 0; c < 16; ++c) {
        const int off = c * 1024 + wv * 256 + ln * 4;
        gload16(zblk + off, &z_lds[off]);
    }

    // ---- per-row |z|^2 from global (L2-hit; overlaps DMA) ----
#pragma unroll
    for (int it = 0; it < 16; ++it) {
        const int r = it * 4 + wv;
        const float4 v = *reinterpret_cast<const float4*>(zblk + r * 256 + ln * 4);
        float s = fmaf(v.x, v.x, fmaf(v.y, v.y, fmaf(v.z, v.z, v.w * v.w)));
#pragma unroll
        for (int o = 32; o > 0; o >>= 1) s += __shfl_xor(s, o);
        if (ln == 0) znbuf[r] = s;
    }

    WAITVM(0);
    __syncthreads();   // z_lds + znbuf ready; no barriers after this point

    float best[16];
    int   bidx[16];
#pragma unroll
    for (int m = 0; m < 16; ++m) { best[m] = 3.4e38f; bidx[m] = 0; }

    const int zbase = wv * 4096 + dq * 4;   // row wv*16, quarter dq

    float4 eA0, eA1, eA2, eA3, eB0, eB1, eB2, eB3;
    LOADE(eA0, eA1, eA2, eA3, 0, 0)        // prologue: kc=0, dc=0

#pragma unroll 1
    for (int kc = 0; kc < 16; ++kc) {       // 64 codes per chunk
        float acc[16][4];
#pragma unroll
        for (int m = 0; m < 16; ++m)
#pragma unroll
            for (int c = 0; c < 4; ++c) acc[m][c] = 0.f;

        float en0 = enorm_g[kc * 64 + tx];
        float en1 = enorm_g[kc * 64 + 16 + tx];
        float en2 = enorm_g[kc * 64 + 32 + tx];
        float en3 = enorm_g[kc * 64 + 48 + tx];

        // ---- dc pipeline: load(d+1); comp(d); load(d+2); comp(d+1) ----
#pragma unroll 1
        for (int dc = 0; dc < 14; dc += 2) {
            LOADE(eB0, eB1, eB2, eB3, kc, dc + 1)
            COMP(eA0, eA1, eA2, eA3, dc)
            LOADE(eA0, eA1, eA2, eA3, kc, dc + 2)
            COMP(eB0, eB1, eB2, eB3, dc + 1)
        }
        LOADE(eB0, eB1, eB2, eB3, kc, 15)
        COMP(eA0, eA1, eA2, eA3, 14)
        if (kc < 15) LOADE(eA0, eA1, eA2, eA3, kc + 1, 0)   // cross-kc prefetch
        COMP(eB0, eB1, eB2, eB3, 15)

        // ---- chunk epilogue: quad combine, dist, argmin ----
#pragma unroll
        for (int m = 0; m < 16; ++m) {
            const float znm = znbuf[wv * 16 + m];
#pragma unroll
            for (int c = 0; c < 4; ++c) {
                float dot = acc[m][c];
                dot += __shfl_xor(dot, 1);
                dot += __shfl_xor(dot, 2);
                const float en = (c == 0) ? en0 : (c == 1) ? en1 : (c == 2) ? en2 : en3;
                const float dist = fmaf(-2.f, dot, znm + en);
                const int col = kc * 64 + c * 16 + tx;   // ascending scan order
                if (dist < best[m]) { best[m] = dist; bidx[m] = col; }
            }
        }
    }

    // ---- cross-tx butterfly (lane bits 2..5), lowest-index tie-break ----
#pragma unroll
    for (int m = 0; m < 16; ++m) {
#pragma unroll
        for (int off = 4; off < 64; off <<= 1) {
            const float ov = __shfl_xor(best[m], off);
            const int   oi = __shfl_xor(bidx[m], off);
            if (ov < best[m] || (ov == best[m] && oi < bidx[m])) {
                best[m] = ov; bidx[m] = oi;
            }
        }
    }
    if (ln == 0) {
        float* o = idx_out + (size_t)blockIdx.x * 64 + wv * 16;
#pragma unroll
        for (int m = 0; m < 16; ++m) o[m] = (float)bidx[m];
    }
}

// ---------------- kernel 2: gather + quantized output + loss partials ----------------
__global__ __launch_bounds__(256)
void gather_kernel(const float* __restrict__ z, const float* __restrict__ emb,
                   const float* __restrict__ idx_f, float* __restrict__ q_out,
                   float* __restrict__ partials) {
    const int wv = threadIdx.x >> 6, ln = threadIdx.x & 63;
    float lsum = 0.f;
#pragma unroll
    for (int i = 0; i < 16; ++i) {
        const size_t row = (size_t)blockIdx.x * 64 + i * 4 + wv;
        const int kidx = (int)idx_f[row];
        const float4 e4 = *reinterpret_cast<const float4*>(emb + (size_t)kidx * 256 + ln * 4);
        const float4 z4 = *reinterpret_cast<const float4*>(z + row * 256 + ln * 4);
        *reinterpret_cast<float4*>(q_out + row * 256 + ln * 4) = e4;  // quantized_st == quantized
        const float dx = e4.x - z4.x, dy = e4.y - z4.y, dz = e4.z - z4.z, dw = e4.w - z4.w;
        lsum += dx * dx + dy * dy + dz * dz + dw * dw;
    }
#pragma unroll
    for (int off = 32; off > 0; off >>= 1) lsum += __shfl_xor(lsum, off);
    __shared__ float red[4];
    if (ln == 0) red[wv] = lsum;
    __syncthreads();
    if (threadIdx.x == 0) partials[blockIdx.x] = red[0] + red[1] + red[2] + red[3];
}

// ---------------- kernel 3: deterministic loss reduction ----------------
__global__ __launch_bounds__(256)
void loss_kernel(const float* __restrict__ partials, float* __restrict__ loss_out) {
    const int tid = threadIdx.x;
    float s = partials[tid] + partials[tid + 256] + partials[tid + 512] + partials[tid + 768];
#pragma unroll
    for (int off = 32; off > 0; off >>= 1) s += __shfl_xor(s, off);
    __shared__ float red[4];
    if ((tid & 63) == 0) red[tid >> 6] = s;
    __syncthreads();
    if (tid == 0)
        loss_out[0] = (red[0] + red[1] + red[2] + red[3]) * (1.25f / 16777216.0f);
}

extern "C" void kernel_launch(void* const* d_in, const int* in_sizes, int n_in,
                              void* d_out, int out_size, void* d_ws, size_t ws_size,
                              hipStream_t stream) {
    const float* z   = (const float*)d_in[0];
    const float* emb = (const float*)d_in[1];
    float* out      = (float*)d_out;
    float* q_out    = out;                       // 16,777,216 floats
    float* loss_out = out + 16777216;            // 1 float
    float* idx_out  = out + 16777217;            // 65,536 floats
    float* enorm    = (float*)d_ws;              // 1024 floats
    float* partials = (float*)d_ws + 1024;       // 1024 floats

    enorm_kernel<<<256, 256, 0, stream>>>(emb, enorm);
    argmin_kernel<<<1024, 256, 0, stream>>>(z, emb, enorm, idx_out);
    gather_kernel<<<1024, 256, 0, stream>>>(z, emb, idx_out, q_out, partials);
    loss_kernel<<<1, 256, 0, stream>>>(partials, loss_out);
}

// Round 7
// 912.916 us; speedup vs baseline: 1.0005x; 1.0005x over previous
//
#include <hip/hip_runtime.h>
#include <stdint.h>

// VectorQuantizer — z:(16,256,64,64) f32 -> 65536 rows of 256; emb:(1024,256) f32.
// d_out: q[16777216] | vq_loss[1] | idx_as_float[65536]
//
// R6: R5 + software-pipelined e-loads (named-register double buffer, depth 1,
// pipelined across dc and across kc). R5 showed VALUBusy=46% with zero
// conflicts and zero spill: per-iteration L2 latency was exposed because
// e-loads were consumed in the issuing iteration. FMA order per accumulator
// is IDENTICAL to R5 -> bit-identical results.

#define WAITVM(N) asm volatile("s_waitcnt vmcnt(" #N ")" ::: "memory")

__device__ __forceinline__ void gload16(const float* gp, float* lp) {
    __builtin_amdgcn_global_load_lds(
        (const __attribute__((address_space(1))) void*)gp,
        (__attribute__((address_space(3))) void*)lp, 16, 0, 0);
}

// ---------------- kernel 0: embedding row norms ----------------
__global__ __launch_bounds__(256)
void enorm_kernel(const float* __restrict__ emb, float* __restrict__ enorm) {
    const int wv = threadIdx.x >> 6, ln = threadIdx.x & 63;
    const int k = blockIdx.x * 4 + wv;
    const float4 v = *reinterpret_cast<const float4*>(emb + (size_t)k * 256 + ln * 4);
    float s = v.x * v.x + v.y * v.y + v.z * v.z + v.w * v.w;
#pragma unroll
    for (int off = 32; off > 0; off >>= 1) s += __shfl_xor(s, off);
    if (ln == 0) enorm[k] = s;
}

// ---------------- kernel 1: argmin (dq-specialized, e-pipelined) ----------------
// 256 thr = 4 waves. Wave wv owns rows wv*16+m (m=0..15).
// Lane: dq = tid&3 (d-quarter), tx = (tid>>2)&15 (code lane).
// Chunk kc (64 codes): thread's codes = kc*64 + c*16 + tx, c=0..3.

#define LOADE(E0, E1, E2, E3, KC, DC) { \
    const float* eb_ = emb + (size_t)((KC) * 64 + tx) * 256 + (DC) * 16 + dq * 4; \
    E0 = *reinterpret_cast<const float4*>(eb_); \
    E1 = *reinterpret_cast<const float4*>(eb_ + 16 * 256); \
    E2 = *reinterpret_cast<const float4*>(eb_ + 32 * 256); \
    E3 = *reinterpret_cast<const float4*>(eb_ + 48 * 256); }

#define COMP(E0, E1, E2, E3, DC) { \
    _Pragma("unroll") \
    for (int m = 0; m < 16; ++m) { \
        const float4 a = *reinterpret_cast<const float4*>( \
            &z_lds[zbase + m * 256 + (DC) * 16]);   /* 16-lane broadcast */ \
        acc[m][0] = fmaf(a.x, E0.x, acc[m][0]); acc[m][0] = fmaf(a.y, E0.y, acc[m][0]); \
        acc[m][0] = fmaf(a.z, E0.z, acc[m][0]); acc[m][0] = fmaf(a.w, E0.w, acc[m][0]); \
        acc[m][1] = fmaf(a.x, E1.x, acc[m][1]); acc[m][1] = fmaf(a.y, E1.y, acc[m][1]); \
        acc[m][1] = fmaf(a.z, E1.z, acc[m][1]); acc[m][1] = fmaf(a.w, E1.w, acc[m][1]); \
        acc[m][2] = fmaf(a.x, E2.x, acc[m][2]); acc[m][2] = fmaf(a.y, E2.y, acc[m][2]); \
        acc[m][2] = fmaf(a.z, E2.z, acc[m][2]); acc[m][2] = fmaf(a.w, E2.w, acc[m][2]); \
        acc[m][3] = fmaf(a.x, E3.x, acc[m][3]); acc[m][3] = fmaf(a.y, E3.y, acc[m][3]); \
        acc[m][3] = fmaf(a.z, E3.z, acc[m][3]); acc[m][3] = fmaf(a.w, E3.w, acc[m][3]); } }

__global__ __launch_bounds__(256, 1)
void argmin_kernel(const float* __restrict__ z, const float* __restrict__ emb,
                   const float* __restrict__ enorm_g, float* __restrict__ idx_out) {
    __shared__ float z_lds[16384];   // [row][d] linear, 64 KB
    __shared__ float znbuf[64];

    const int tid = threadIdx.x;
    const int dq = tid & 3;
    const int tx = (tid >> 2) & 15;
    const int wv = tid >> 6;
    const int ln = tid & 63;

    const float* zblk = z + (size_t)blockIdx.x * 16384;

    // ---- DMA z tile to LDS (linear dest = linear source) ----
#pragma unroll
    for (int c = 0; c < 16; ++c) {
        const int off = c * 1024 + wv * 256 + ln * 4;
        gload16(zblk + off, &z_lds[off]);
    }

    // ---- per-row |z|^2 from global (L2-hit; overlaps DMA) ----
#pragma unroll
    for (int it = 0; it < 16; ++it) {
        const int r = it * 4 + wv;
        const float4 v = *reinterpret_cast<const float4*>(zblk + r * 256 + ln * 4);
        float s = fmaf(v.x, v.x, fmaf(v.y, v.y, fmaf(v.z, v.z, v.w * v.w)));
#pragma unroll
        for (int o = 32; o > 0; o >>= 1) s += __shfl_xor(s, o);
        if (ln == 0) znbuf[r] = s;
    }

    WAITVM(0);
    __syncthreads();   // z_lds + znbuf ready; no barriers after this point

    float best[16];
    int   bidx[16];
#pragma unroll
    for (int m = 0; m < 16; ++m) { best[m] = 3.4e38f; bidx[m] = 0; }

    const int zbase = wv * 4096 + dq * 4;   // row wv*16, quarter dq

    float4 eA0, eA1, eA2, eA3, eB0, eB1, eB2, eB3;
    LOADE(eA0, eA1, eA2, eA3, 0, 0)        // prologue: kc=0, dc=0

#pragma unroll 1
    for (int kc = 0; kc < 16; ++kc) {       // 64 codes per chunk
        float acc[16][4];
#pragma unroll
        for (int m = 0; m < 16; ++m)
#pragma unroll
            for (int c = 0; c < 4; ++c) acc[m][c] = 0.f;

        float en0 = enorm_g[kc * 64 + tx];
        float en1 = enorm_g[kc * 64 + 16 + tx];
        float en2 = enorm_g[kc * 64 + 32 + tx];
        float en3 = enorm_g[kc * 64 + 48 + tx];

        // ---- dc pipeline: load(d+1); comp(d); load(d+2); comp(d+1) ----
#pragma unroll 1
        for (int dc = 0; dc < 14; dc += 2) {
            LOADE(eB0, eB1, eB2, eB3, kc, dc + 1)
            COMP(eA0, eA1, eA2, eA3, dc)
            LOADE(eA0, eA1, eA2, eA3, kc, dc + 2)
            COMP(eB0, eB1, eB2, eB3, dc + 1)
        }
        LOADE(eB0, eB1, eB2, eB3, kc, 15)
        COMP(eA0, eA1, eA2, eA3, 14)
        if (kc < 15) LOADE(eA0, eA1, eA2, eA3, kc + 1, 0)   // cross-kc prefetch
        COMP(eB0, eB1, eB2, eB3, 15)

        // ---- chunk epilogue: quad combine, dist, argmin ----
#pragma unroll
        for (int m = 0; m < 16; ++m) {
            const float znm = znbuf[wv * 16 + m];
#pragma unroll
            for (int c = 0; c < 4; ++c) {
                float dot = acc[m][c];
                dot += __shfl_xor(dot, 1);
                dot += __shfl_xor(dot, 2);
                const float en = (c == 0) ? en0 : (c == 1) ? en1 : (c == 2) ? en2 : en3;
                const float dist = fmaf(-2.f, dot, znm + en);
                const int col = kc * 64 + c * 16 + tx;   // ascending scan order
                if (dist < best[m]) { best[m] = dist; bidx[m] = col; }
            }
        }
    }

    // ---- cross-tx butterfly (lane bits 2..5), lowest-index tie-break ----
#pragma unroll
    for (int m = 0; m < 16; ++m) {
#pragma unroll
        for (int off = 4; off < 64; off <<= 1) {
            const float ov = __shfl_xor(best[m], off);
            const int   oi = __shfl_xor(bidx[m], off);
            if (ov < best[m] || (ov == best[m] && oi < bidx[m])) {
                best[m] = ov; bidx[m] = oi;
            }
        }
    }
    if (ln == 0) {
        float* o = idx_out + (size_t)blockIdx.x * 64 + wv * 16;
#pragma unroll
        for (int m = 0; m < 16; ++m) o[m] = (float)bidx[m];
    }
}

// ---------------- kernel 2: gather + quantized output + loss partials ----------------
__global__ __launch_bounds__(256)
void gather_kernel(const float* __restrict__ z, const float* __restrict__ emb,
                   const float* __restrict__ idx_f, float* __restrict__ q_out,
                   float* __restrict__ partials) {
    const int wv = threadIdx.x >> 6, ln = threadIdx.x & 63;
    float lsum = 0.f;
#pragma unroll
    for (int i = 0; i < 16; ++i) {
        const size_t row = (size_t)blockIdx.x * 64 + i * 4 + wv;
        const int kidx = (int)idx_f[row];
        const float4 e4 = *reinterpret_cast<const float4*>(emb + (size_t)kidx * 256 + ln * 4);
        const float4 z4 = *reinterpret_cast<const float4*>(z + row * 256 + ln * 4);
        *reinterpret_cast<float4*>(q_out + row * 256 + ln * 4) = e4;  // quantized_st == quantized
        const float dx = e4.x - z4.x, dy = e4.y - z4.y, dz = e4.z - z4.z, dw = e4.w - z4.w;
        lsum += dx * dx + dy * dy + dz * dz + dw * dw;
    }
#pragma unroll
    for (int off = 32; off > 0; off >>= 1) lsum += __shfl_xor(lsum, off);
    __shared__ float red[4];
    if (ln == 0) red[wv] = lsum;
    __syncthreads();
    if (threadIdx.x == 0) partials[blockIdx.x] = red[0] + red[1] + red[2] + red[3];
}

// ---------------- kernel 3: deterministic loss reduction ----------------
__global__ __launch_bounds__(256)
void loss_kernel(const float* __restrict__ partials, float* __restrict__ loss_out) {
    const int tid = threadIdx.x;
    float s = partials[tid] + partials[tid + 256] + partials[tid + 512] + partials[tid + 768];
#pragma unroll
    for (int off = 32; off > 0; off >>= 1) s += __shfl_xor(s, off);
    __shared__ float red[4];
    if ((tid & 63) == 0) red[tid >> 6] = s;
    __syncthreads();
    if (tid == 0)
        loss_out[0] = (red[0] + red[1] + red[2] + red[3]) * (1.25f / 16777216.0f);
}

extern "C" void kernel_launch(void* const* d_in, const int* in_sizes, int n_in,
                              void* d_out, int out_size, void* d_ws, size_t ws_size,
                              hipStream_t stream) {
    const float* z   = (const float*)d_in[0];
    const float* emb = (const float*)d_in[1];
    float* out      = (float*)d_out;
    float* q_out    = out;                       // 16,777,216 floats
    float* loss_out = out + 16777216;            // 1 float
    float* idx_out  = out + 16777217;            // 65,536 floats
    float* enorm    = (float*)d_ws;              // 1024 floats
    float* partials = (float*)d_ws + 1024;       // 1024 floats

    enorm_kernel<<<256, 256, 0, stream>>>(emb, enorm);
    argmin_kernel<<<1024, 256, 0, stream>>>(z, emb, enorm, idx_out);
    gather_kernel<<<1024, 256, 0, stream>>>(z, emb, idx_out, q_out, partials);
    loss_kernel<<<1, 256, 0, stream>>>(partials, loss_out);
}

// Round 8
// 577.326 us; speedup vs baseline: 1.5821x; 1.5813x over previous
//
#include <hip/hip_runtime.h>
#include <stdint.h>

// VectorQuantizer — z:(16,256,64,64) f32 -> 65536 rows of 256; emb:(1024,256) f32.
// d_out: q[16777216] | vq_loss[1] | idx_as_float[65536]
//
// R7: occupancy fix. R5/R6 ran at ~1 wave/SIMD (OccupancyPercent 12%) ->
// VALUBusy pinned at ~50% regardless of ILP (R6's reg-pipelining regressed).
// This round: TILE_M=32 (32KB z-tile -> 4 blocks/CU) + acc[8][4] (VGPR ~100,
// capped 128 via __launch_bounds__(256,4) -> 4 waves/SIMD). Same dq-specialized
// structure and bit-identical per-(row,code) FMA order as R5 (passed 3x).

#define WAITVM(N) asm volatile("s_waitcnt vmcnt(" #N ")" ::: "memory")

__device__ __forceinline__ void gload16(const float* gp, float* lp) {
    __builtin_amdgcn_global_load_lds(
        (const __attribute__((address_space(1))) void*)gp,
        (__attribute__((address_space(3))) void*)lp, 16, 0, 0);
}

// ---------------- kernel 0: embedding row norms ----------------
__global__ __launch_bounds__(256)
void enorm_kernel(const float* __restrict__ emb, float* __restrict__ enorm) {
    const int wv = threadIdx.x >> 6, ln = threadIdx.x & 63;
    const int k = blockIdx.x * 4 + wv;
    const float4 v = *reinterpret_cast<const float4*>(emb + (size_t)k * 256 + ln * 4);
    float s = v.x * v.x + v.y * v.y + v.z * v.z + v.w * v.w;
#pragma unroll
    for (int off = 32; off > 0; off >>= 1) s += __shfl_xor(s, off);
    if (ln == 0) enorm[k] = s;
}

// ---------------- kernel 1: argmin (dq-specialized, occupancy-sized) ----------------
// 256 thr = 4 waves; block owns 32 rows; wave wv owns rows wv*8+m (m=0..7).
// Lane: dq = tid&3 (d-quarter), tx = (tid>>2)&15 (code lane).
// Chunk kc (64 codes): thread's codes = kc*64 + c*16 + tx, c=0..3.
__global__ __launch_bounds__(256, 4)
void argmin_kernel(const float* __restrict__ z, const float* __restrict__ emb,
                   const float* __restrict__ enorm_g, float* __restrict__ idx_out) {
    __shared__ float z_lds[8192];    // [row][d] linear, 32 KB (32 rows)
    __shared__ float znbuf[32];

    const int tid = threadIdx.x;
    const int dq = tid & 3;
    const int tx = (tid >> 2) & 15;
    const int wv = tid >> 6;
    const int ln = tid & 63;

    const float* zblk = z + (size_t)blockIdx.x * 8192;

    // ---- DMA z tile to LDS (linear dest = linear source) ----
#pragma unroll
    for (int c = 0; c < 8; ++c) {
        const int off = c * 1024 + wv * 256 + ln * 4;
        gload16(zblk + off, &z_lds[off]);
    }

    // ---- per-row |z|^2 from global (L2-hit; overlaps DMA) ----
#pragma unroll
    for (int it = 0; it < 8; ++it) {
        const int r = it * 4 + wv;
        const float4 v = *reinterpret_cast<const float4*>(zblk + r * 256 + ln * 4);
        float s = fmaf(v.x, v.x, fmaf(v.y, v.y, fmaf(v.z, v.z, v.w * v.w)));
#pragma unroll
        for (int o = 32; o > 0; o >>= 1) s += __shfl_xor(s, o);
        if (ln == 0) znbuf[r] = s;
    }

    WAITVM(0);
    __syncthreads();   // z_lds + znbuf ready; no barriers after this point

    float best[8];
    int   bidx[8];
#pragma unroll
    for (int m = 0; m < 8; ++m) { best[m] = 3.4e38f; bidx[m] = 0; }

    const int zbase = wv * 2048 + dq * 4;   // row wv*8, quarter dq

#pragma unroll 1
    for (int kc = 0; kc < 16; ++kc) {       // 64 codes per chunk
        float acc[8][4];
#pragma unroll
        for (int m = 0; m < 8; ++m)
#pragma unroll
            for (int c = 0; c < 4; ++c) acc[m][c] = 0.f;

        const float en0 = enorm_g[kc * 64 + tx];
        const float en1 = enorm_g[kc * 64 + 16 + tx];
        const float en2 = enorm_g[kc * 64 + 32 + tx];
        const float en3 = enorm_g[kc * 64 + 48 + tx];

#pragma unroll 1
        for (int dc = 0; dc < 16; ++dc) {
            // e: 4 float4 global loads; each dq-quad consumes a contiguous 64B line;
            // addresses are identical across the block's 4 waves -> L1 dedup.
            const float* eb = emb + (size_t)(kc * 64 + tx) * 256 + dc * 16 + dq * 4;
            const float4 e0 = *reinterpret_cast<const float4*>(eb);
            const float4 e1 = *reinterpret_cast<const float4*>(eb + 16 * 256);
            const float4 e2 = *reinterpret_cast<const float4*>(eb + 32 * 256);
            const float4 e3 = *reinterpret_cast<const float4*>(eb + 48 * 256);
#pragma unroll
            for (int m = 0; m < 8; ++m) {
                const float4 a = *reinterpret_cast<const float4*>(
                    &z_lds[zbase + m * 256 + dc * 16]);   // 16-lane broadcast read
                acc[m][0] = fmaf(a.x, e0.x, acc[m][0]); acc[m][0] = fmaf(a.y, e0.y, acc[m][0]);
                acc[m][0] = fmaf(a.z, e0.z, acc[m][0]); acc[m][0] = fmaf(a.w, e0.w, acc[m][0]);
                acc[m][1] = fmaf(a.x, e1.x, acc[m][1]); acc[m][1] = fmaf(a.y, e1.y, acc[m][1]);
                acc[m][1] = fmaf(a.z, e1.z, acc[m][1]); acc[m][1] = fmaf(a.w, e1.w, acc[m][1]);
                acc[m][2] = fmaf(a.x, e2.x, acc[m][2]); acc[m][2] = fmaf(a.y, e2.y, acc[m][2]);
                acc[m][2] = fmaf(a.z, e2.z, acc[m][2]); acc[m][2] = fmaf(a.w, e2.w, acc[m][2]);
                acc[m][3] = fmaf(a.x, e3.x, acc[m][3]); acc[m][3] = fmaf(a.y, e3.y, acc[m][3]);
                acc[m][3] = fmaf(a.z, e3.z, acc[m][3]); acc[m][3] = fmaf(a.w, e3.w, acc[m][3]);
            }
        }

        // ---- chunk epilogue: quad combine, dist, argmin ----
#pragma unroll
        for (int m = 0; m < 8; ++m) {
            const float znm = znbuf[wv * 8 + m];
#pragma unroll
            for (int c = 0; c < 4; ++c) {
                float dot = acc[m][c];
                dot += __shfl_xor(dot, 1);
                dot += __shfl_xor(dot, 2);
                const float en = (c == 0) ? en0 : (c == 1) ? en1 : (c == 2) ? en2 : en3;
                const float dist = fmaf(-2.f, dot, znm + en);
                const int col = kc * 64 + c * 16 + tx;   // ascending scan order
                if (dist < best[m]) { best[m] = dist; bidx[m] = col; }
            }
        }
    }

    // ---- cross-tx butterfly (lane bits 2..5), lowest-index tie-break ----
#pragma unroll
    for (int m = 0; m < 8; ++m) {
#pragma unroll
        for (int off = 4; off < 64; off <<= 1) {
            const float ov = __shfl_xor(best[m], off);
            const int   oi = __shfl_xor(bidx[m], off);
            if (ov < best[m] || (ov == best[m] && oi < bidx[m])) {
                best[m] = ov; bidx[m] = oi;
            }
        }
    }
    if (ln == 0) {
        float* o = idx_out + (size_t)blockIdx.x * 32 + wv * 8;
#pragma unroll
        for (int m = 0; m < 8; ++m) o[m] = (float)bidx[m];
    }
}

// ---------------- kernel 2: gather + quantized output + loss partials ----------------
__global__ __launch_bounds__(256)
void gather_kernel(const float* __restrict__ z, const float* __restrict__ emb,
                   const float* __restrict__ idx_f, float* __restrict__ q_out,
                   float* __restrict__ partials) {
    const int wv = threadIdx.x >> 6, ln = threadIdx.x & 63;
    float lsum = 0.f;
#pragma unroll
    for (int i = 0; i < 16; ++i) {
        const size_t row = (size_t)blockIdx.x * 64 + i * 4 + wv;
        const int kidx = (int)idx_f[row];
        const float4 e4 = *reinterpret_cast<const float4*>(emb + (size_t)kidx * 256 + ln * 4);
        const float4 z4 = *reinterpret_cast<const float4*>(z + row * 256 + ln * 4);
        *reinterpret_cast<float4*>(q_out + row * 256 + ln * 4) = e4;  // quantized_st == quantized
        const float dx = e4.x - z4.x, dy = e4.y - z4.y, dz = e4.z - z4.z, dw = e4.w - z4.w;
        lsum += dx * dx + dy * dy + dz * dz + dw * dw;
    }
#pragma unroll
    for (int off = 32; off > 0; off >>= 1) lsum += __shfl_xor(lsum, off);
    __shared__ float red[4];
    if (ln == 0) red[wv] = lsum;
    __syncthreads();
    if (threadIdx.x == 0) partials[blockIdx.x] = red[0] + red[1] + red[2] + red[3];
}

// ---------------- kernel 3: deterministic loss reduction ----------------
__global__ __launch_bounds__(256)
void loss_kernel(const float* __restrict__ partials, float* __restrict__ loss_out) {
    const int tid = threadIdx.x;
    float s = partials[tid] + partials[tid + 256] + partials[tid + 512] + partials[tid + 768];
#pragma unroll
    for (int off = 32; off > 0; off >>= 1) s += __shfl_xor(s, off);
    __shared__ float red[4];
    if ((tid & 63) == 0) red[tid >> 6] = s;
    __syncthreads();
    if (tid == 0)
        loss_out[0] = (red[0] + red[1] + red[2] + red[3]) * (1.25f / 16777216.0f);
}

extern "C" void kernel_launch(void* const* d_in, const int* in_sizes, int n_in,
                              void* d_out, int out_size, void* d_ws, size_t ws_size,
                              hipStream_t stream) {
    const float* z   = (const float*)d_in[0];
    const float* emb = (const float*)d_in[1];
    float* out      = (float*)d_out;
    float* q_out    = out;                       // 16,777,216 floats
    float* loss_out = out + 16777216;            // 1 float
    float* idx_out  = out + 16777217;            // 65,536 floats
    float* enorm    = (float*)d_ws;              // 1024 floats
    float* partials = (float*)d_ws + 1024;       // 1024 floats

    enorm_kernel<<<256, 256, 0, stream>>>(emb, enorm);
    argmin_kernel<<<2048, 256, 0, stream>>>(z, emb, enorm, idx_out);
    gather_kernel<<<1024, 256, 0, stream>>>(z, emb, idx_out, q_out, partials);
    loss_kernel<<<1, 256, 0, stream>>>(partials, loss_out);
}